// Round 7
// baseline (222.569 us; speedup 1.0000x reference)
//
#include <hip/hip_runtime.h>

// TV denoiser (Chambolle-Pock), 40 iterations = 5 launches x 8 fused steps.
// Temporal blocking, packed float4 state (x2,u0,u1,y) ping-pong (r18: -10us).
//
// Round-19: 2 columns per lane -> 64x128 staged, 48x112 output per block.
//   r18 post-mortem: packed staging won only ~2us/dispatch; VALUBusy ~50%,
//   HBM 18%, conflicts 0 -> residual stall is (a) DS/shfl pipe (17 shfl per
//   wave-step on the critical path), (b) 968 blocks @3/CU = 1.26 scheduling
//   rounds (200-block tail at 26% util), (c) 56% halo-compute efficiency.
//   Fix: lane owns ADJACENT column pair (2lc, 2lc+1). Horizontal neighbor of
//   one column is an own register -> per row ONE shfl_up + ONE shfl_down
//   serves BOTH columns: DS ops/cell halve. Grid 5x11x8 = 440 blocks -> one
//   resident round at 2 blocks/CU. Staged-work efficiency 56->59%.
//   Registers: 80 state + 4 tm + misc ~100 -> __launch_bounds__(512,2)
//   (2nd arg = blocks/CU empirically, rounds 8/9/15/16) = 128-VGPR cap.
//   SPILL SENTINEL: WRITE ~33MB/mid-dispatch; VGPR <= 128; FETCH ~57MB.
//   Per-cell arithmetic op-for-op identical to r18 -> absmax 0.015625.
//
// Structure: 512 thr = 8 waves; wave s owns rows 8s..8s+7, lane lc owns
// cols 2lc,2lc+1 of the 128-col staged region, all in REGISTERS. Vertical
// neighbors: registers (LDS u0B/wTop for strip boundaries, stride-1 float2
// = 2-way bank aliasing, free per m136). Horizontal: in-register for the
// pair-interior, __shfl_up(u1[i][1])/__shfl_down(w[i][0]) across lanes
// (VERIFIED wave-wide on gfx950; DPP mis-shifts at 16-lane boundaries).
// Lane/lcol edge garbage harmless: cols 0/127 have tm=0, feed only frozen
// cells (cone argument). Masks: ph1 unconditional; ph2 freeze via r/rh=0
// (NaN-safe: operands finite, rsq(0)=inf dies in fmin). sewf/sigBot fold
// forward-diff edge masks. first: u=0, x2=y. last: store x2 only.

#define Hh 512
#define Ww 512
#define Bb 8
#define TSC 112        // output cols per block
#define TSR 48         // output rows per block
#define KF 8
#define SC 128         // staged cols
#define SR 64          // staged rows
#define NT 512
#define RS 8           // rows per thread

// ---------------------------------------------------------------- packed --
__global__ __launch_bounds__(NT, 2)
void tv_packed(const float*  __restrict__ y_in,
               const float4* __restrict__ st_in,
               float4* __restrict__ st_out,
               float*  __restrict__ x2_out,
               int first, int last)
{
    constexpr float TAU = 0.01f;
    constexpr float RHO = 1.99f;
    constexpr float HRHO = 0.995f;       // 0.5*RHO
    constexpr float SIGMA = 12.5f;       // 1/TAU/8
    constexpr float THS = 0.1f;
    constexpr float INV_1PT = 1.0f / 1.01f;

    __shared__ float u0B [9 * SC];   // u0 of row 8s-1 (strip s-1 bottom); s=0 zeros
    __shared__ float wTop[9 * SC];   // w  of row 8s   (strip s top);     s=8 zeros

    const int b   = blockIdx.z;
    const int r0  = blockIdx.y * TSR;
    const int c0  = blockIdx.x * TSC;
    const int tid = threadIdx.x;
    const size_t plane = (size_t)b * (Hh * Ww);

    const int s     = tid >> 6;          // wave id
    const int lc    = tid & 63;          // lane id
    const int lcol0 = 2 * lc;            // first owned staged column
    const int gc0   = c0 - KF + lcol0;   // global col of c=0
    const bool colin0 = (gc0 >= 0) & (gc0 < Ww);
    const bool colin1 = (gc0 + 1 >= 0) & (gc0 + 1 < Ww);
    const float sewf0 = (gc0     < Ww - 1) ? SIGMA : 0.f;
    const float sewf1 = (gc0 + 1 < Ww - 1) ? SIGMA : 0.f;
    const int lr0 = RS * s;
    const int gr0 = r0 - KF + lr0;
    const float sigBot = (gr0 + RS - 1 == Hh - 1) ? 0.f : SIGMA;

    if (tid < SC) { u0B[tid] = 0.f; wTop[8 * SC + tid] = 0.f; }

    float x2[RS][2], u0[RS][2], u1[RS][2], yv[RS][2], w[RS][2];
    unsigned tmp[4] = {0u, 0u, 0u, 0u};  // 16 tm bytes

    // ---- stage: branchless, wide loads
    #pragma unroll
    for (int i = 0; i < RS; ++i) {
        const int gr = gr0 + i;
        const int lr = lr0 + i;
        const bool rin = (gr >= 0) & (gr < Hh);
        #pragma unroll
        for (int c = 0; c < 2; ++c) {
            const bool img = rin & (c ? colin1 : colin0);
            const size_t gi = img ? (plane + (size_t)gr * Ww + (gc0 + c)) : plane;
            if (first) {
                float cy = y_in[gi]; cy = img ? cy : 0.f;
                x2[i][c] = cy; yv[i][c] = cy; u0[i][c] = 0.f; u1[i][c] = 0.f;
            } else {
                float4 st = st_in[gi];
                x2[i][c] = img ? st.x : 0.f;
                u0[i][c] = img ? st.y : 0.f;
                u1[i][c] = img ? st.z : 0.f;
                yv[i][c] = img ? st.w : 0.f;
            }
            const int lcol = lcol0 + c;
            unsigned tm = img ? (unsigned)min(min(lr, SR - 1 - lr),
                                              min(lcol, SC - 1 - lcol)) : 0u;
            const int k = 2 * i + c;
            tmp[k >> 2] |= tm << (8 * (k & 3));
        }
    }
    *(float2*)&u0B[(s + 1) * SC + lcol0] = make_float2(u0[RS - 1][0], u0[RS - 1][1]);
    __syncthreads();

    for (int t = 0; t < KF; ++t) {
        // ---- phase 1: w = 2x - x2 (unconditional; garbage stays in cone)
        {
            float2 ua2 = *(float2*)&u0B[s * SC + lcol0];
            #pragma unroll
            for (int i = 0; i < RS; ++i) {
                float ul0 = __shfl_up(u1[i][1], 1, 64);  // col lcol0-1 (lane lc-1's c=1)
                float ul1 = u1[i][0];                    // own register
                float ua_0 = (i == 0) ? ua2.x : u0[i - 1][0];
                float ua_1 = (i == 0) ? ua2.y : u0[i - 1][1];
                float adj0 = ua_0 - u0[i][0] + ul0 - u1[i][0];
                float adj1 = ua_1 - u0[i][1] + ul1 - u1[i][1];
                float xv0 = fmaf(TAU, yv[i][0] - adj0, x2[i][0]);
                float xv1 = fmaf(TAU, yv[i][1] - adj1, x2[i][1]);
                w[i][0] = fmaf(2.0f * INV_1PT, xv0, -x2[i][0]);
                w[i][1] = fmaf(2.0f * INV_1PT, xv1, -x2[i][1]);
            }
            *(float2*)&wTop[s * SC + lcol0] = make_float2(w[0][0], w[0][1]);
        }
        __syncthreads();
        // ---- phase 2: u, x2 update; freeze via r/rh = 0
        {
            float2 wb2 = *(float2*)&wTop[(s + 1) * SC + lcol0];
            #pragma unroll
            for (int i = 0; i < RS; ++i) {
                float wr1 = __shfl_down(w[i][0], 1, 64); // col lcol0+2 (lane lc+1's c=0)
                float wr0 = w[i][1];                     // own register
                float wb_0 = (i == RS - 1) ? wb2.x : w[i + 1][0];
                float wb_1 = (i == RS - 1) ? wb2.y : w[i + 1][1];
                const float sig_h = (i == RS - 1) ? sigBot : SIGMA;

                float v00 = fmaf(sig_h, wb_0 - w[i][0], u0[i][0]);
                float v10 = fmaf(sewf0, wr0 - w[i][0], u1[i][0]);
                float iv0 = fminf(THS * __builtin_amdgcn_rsqf(fmaf(v00, v00, v10 * v10)), 1.f);
                float v01 = fmaf(sig_h, wb_1 - w[i][1], u0[i][1]);
                float v11 = fmaf(sewf1, wr1 - w[i][1], u1[i][1]);
                float iv1 = fminf(THS * __builtin_amdgcn_rsqf(fmaf(v01, v01, v11 * v11)), 1.f);

                const int k0 = 2 * i, k1 = 2 * i + 1;
                unsigned tm0 = (tmp[k0 >> 2] >> (8 * (k0 & 3))) & 255u;
                unsigned tm1 = (tmp[k1 >> 2] >> (8 * (k1 & 3))) & 255u;
                bool a0 = (unsigned)t < tm0;
                bool a1 = (unsigned)t < tm1;
                float r10 = a0 ? RHO : 0.f, rh0 = a0 ? HRHO : 0.f;
                float r11 = a1 ? RHO : 0.f, rh1 = a1 ? HRHO : 0.f;

                u0[i][0] = fmaf(r10, fmaf(v00, iv0, -u0[i][0]), u0[i][0]);
                u1[i][0] = fmaf(r10, fmaf(v10, iv0, -u1[i][0]), u1[i][0]);
                x2[i][0] = fmaf(rh0, w[i][0] - x2[i][0], x2[i][0]);
                u0[i][1] = fmaf(r11, fmaf(v01, iv1, -u0[i][1]), u0[i][1]);
                u1[i][1] = fmaf(r11, fmaf(v11, iv1, -u1[i][1]), u1[i][1]);
                x2[i][1] = fmaf(rh1, w[i][1] - x2[i][1], x2[i][1]);
            }
            *(float2*)&u0B[(s + 1) * SC + lcol0] = make_float2(u0[RS - 1][0], u0[RS - 1][1]);
        }
        __syncthreads();
    }

    // ---- store central 48x112 straight from registers
    if (s >= 1 && s <= 6) {
        #pragma unroll
        for (int c = 0; c < 2; ++c) {
            const int lcol = lcol0 + c;
            const int gc   = gc0 + c;
            if (lcol >= KF && lcol < KF + TSC && gc < Ww) {
                #pragma unroll
                for (int i = 0; i < RS; ++i) {
                    const int gr = gr0 + i;
                    if (gr < Hh) {
                        const size_t gi = plane + (size_t)gr * Ww + gc;
                        if (last) x2_out[gi] = x2[i][c];
                        else      st_out[gi] = make_float4(x2[i][c], u0[i][c],
                                                           u1[i][c], yv[i][c]);
                    }
                }
            }
        }
    }
}

// ------------------------------------------------- fallback (exact r13) --
#define TS 48
#define S  64

__global__ __launch_bounds__(NT, 3)
void tv_sep(const float*  __restrict__ x2_in,
            const float2* __restrict__ u_in,
            const float*  __restrict__ y_in,
            float*  __restrict__ x2_out,
            float2* __restrict__ u_out,
            int first, int last)
{
    constexpr float TAU = 0.01f;
    constexpr float RHO = 1.99f;
    constexpr float HRHO = 0.995f;
    constexpr float SIGMA = 12.5f;
    constexpr float THS = 0.1f;
    constexpr float INV_1PT = 1.0f / 1.01f;

    __shared__ float u0B [9 * S];
    __shared__ float wTop[9 * S];

    const int b   = blockIdx.z;
    const int r0  = blockIdx.y * TS;
    const int c0  = blockIdx.x * TS;
    const int tid = threadIdx.x;
    const size_t plane = (size_t)b * (Hh * Ww);

    const int s   = tid >> 6;
    const int lc  = tid & 63;
    const int gc  = c0 - KF + lc;
    const bool colin = (gc >= 0) & (gc < Ww);
    const float sewf = (gc < Ww - 1) ? SIGMA : 0.f;
    const int lr0 = RS * s;
    const int gr0 = r0 - KF + lr0;
    const float sigBot = (gr0 + RS - 1 == Hh - 1) ? 0.f : SIGMA;

    if (tid < S) { u0B[tid] = 0.f; wTop[8 * S + tid] = 0.f; }

    float u0[RS], u1[RS], x2[RS], yv[RS], w[RS];
    unsigned tmp0 = 0u, tmp1 = 0u;

    #pragma unroll
    for (int i = 0; i < RS; ++i) {
        const int gr = gr0 + i;
        const int lr = lr0 + i;
        const bool img = colin & (gr >= 0) & (gr < Hh);
        float a = 0.f, c = 0.f, z0 = 0.f, z1 = 0.f;
        if (img) {
            size_t gi = plane + (size_t)gr * Ww + gc;
            c = y_in[gi];
            if (first) a = c;
            else {
                a = x2_in[gi];
                float2 uu = u_in[gi];
                z0 = uu.x; z1 = uu.y;
            }
        }
        u0[i] = z0; u1[i] = z1; x2[i] = a; yv[i] = c;
        unsigned tm = img ? (unsigned)min(min(lr, S - 1 - lr), min(lc, S - 1 - lc)) : 0u;
        if (i < 4) tmp0 |= tm << (8 * i);
        else       tmp1 |= tm << (8 * (i - 4));
    }
    u0B[(s + 1) * S + lc] = u0[RS - 1];
    __syncthreads();

    for (int t = 0; t < KF; ++t) {
        {
            float u0a = u0B[s * S + lc];
            #pragma unroll
            for (int i = 0; i < RS; ++i) {
                float ul = __shfl_up(u1[i], 1, 64);
                float ua = (i == 0) ? u0a : u0[i - 1];
                float adj = ua - u0[i] + ul - u1[i];
                float xv = fmaf(TAU, yv[i] - adj, x2[i]);
                w[i] = fmaf(2.0f * INV_1PT, xv, -x2[i]);
            }
            wTop[s * S + lc] = w[0];
        }
        __syncthreads();
        {
            float wbot = wTop[(s + 1) * S + lc];
            #pragma unroll
            for (int i = 0; i < RS; ++i) {
                float wr = __shfl_down(w[i], 1, 64);
                float wb = (i == RS - 1) ? wbot : w[i + 1];
                const float sig_h = (i == RS - 1) ? sigBot : SIGMA;
                float v0 = fmaf(sig_h, wb - w[i], u0[i]);
                float v1 = fmaf(sewf,  wr - w[i], u1[i]);
                float iv = fminf(THS * __builtin_amdgcn_rsqf(fmaf(v0, v0, v1 * v1)), 1.f);
                unsigned tmb = ((i < 4 ? tmp0 : tmp1) >> (8 * (i & 3))) & 255u;
                bool act = (unsigned)t < tmb;
                float r1 = act ? RHO  : 0.f;
                float rh = act ? HRHO : 0.f;
                u0[i] = fmaf(r1, fmaf(v0, iv, -u0[i]), u0[i]);
                u1[i] = fmaf(r1, fmaf(v1, iv, -u1[i]), u1[i]);
                x2[i] = fmaf(rh, w[i] - x2[i], x2[i]);
            }
            u0B[(s + 1) * S + lc] = u0[RS - 1];
        }
        __syncthreads();
    }

    if (s >= 1 && s <= 6 && lc >= KF && lc < KF + TS && gc < Ww) {
        #pragma unroll
        for (int i = 0; i < RS; ++i) {
            const int gr = gr0 + i;
            if (gr < Hh) {
                size_t gi = plane + (size_t)gr * Ww + gc;
                x2_out[gi] = x2[i];
                if (!last) u_out[gi] = make_float2(u0[i], u1[i]);
            }
        }
    }
}

extern "C" void kernel_launch(void* const* d_in, const int* in_sizes, int n_in,
                              void* d_out, int out_size, void* d_ws, size_t ws_size,
                              hipStream_t stream)
{
    const float* y = (const float*)d_in[0];
    float* out = (float*)d_out;
    const size_t NP = (size_t)Bb * Hh * Ww;   // 2M cells

    if (ws_size >= 2 * NP * sizeof(float4)) {
        // packed path: two 32MiB float4 ping-pong buffers
        float4* stA = (float4*)d_ws;
        float4* stB = stA + NP;
        dim3 grid((Ww + TSC - 1) / TSC, (Hh + TSR - 1) / TSR, Bb);  // 5x11x8 = 440
        tv_packed<<<grid, NT, 0, stream>>>(y, stB, stA, out, 1, 0);  // y -> stA
        tv_packed<<<grid, NT, 0, stream>>>(y, stA, stB, out, 0, 0);
        tv_packed<<<grid, NT, 0, stream>>>(y, stB, stA, out, 0, 0);
        tv_packed<<<grid, NT, 0, stream>>>(y, stA, stB, out, 0, 0);
        tv_packed<<<grid, NT, 0, stream>>>(y, stB, stA, out, 0, 1);  // -> out
    } else {
        // fallback: exact r13 layout (48 MiB)
        float*  ws  = (float*)d_ws;
        float*  x2A = ws;
        float*  x2B = ws + NP;
        float2* uA  = (float2*)(ws + 2 * NP);
        float2* uB  = (float2*)(ws + 4 * NP);
        dim3 grid((Ww + TS - 1) / TS, (Hh + TS - 1) / TS, Bb);      // 11x11x8
        tv_sep<<<grid, NT, 0, stream>>>(y,   uB, y, x2A, uA, 1, 0);
        tv_sep<<<grid, NT, 0, stream>>>(x2A, uA, y, x2B, uB, 0, 0);
        tv_sep<<<grid, NT, 0, stream>>>(x2B, uB, y, x2A, uA, 0, 0);
        tv_sep<<<grid, NT, 0, stream>>>(x2A, uA, y, x2B, uB, 0, 0);
        tv_sep<<<grid, NT, 0, stream>>>(x2B, uB, y, out, uA, 0, 1);
    }
}